// Round 1
// baseline (1136.574 us; speedup 1.0000x reference)
//
#include <hip/hip_runtime.h>

#define CIN 256
#define OC  256

// ---------------------------------------------------------------------------
// Offset conv: 3x3, stride 1, pad 1, CIN=256 -> 18, + bias.
// thread = one pixel, two consecutive output channels.
// grid: (HW/256, 9, B)
// ---------------------------------------------------------------------------
__global__ __launch_bounds__(256) void offset_conv_k(
    const float* __restrict__ x, const float* __restrict__ wgt,
    const float* __restrict__ bias, float* __restrict__ out,
    int H, int W)
{
    const int HW  = H * W;
    const int pix = blockIdx.x * 256 + threadIdx.x;
    const int b   = blockIdx.z;
    const int oc0 = blockIdx.y * 2;
    const int h    = pix / W;
    const int wcol = pix - h * W;

    float acc0 = 0.f, acc1 = 0.f;
    const float* xb = x + (size_t)b * CIN * HW;
    const float* w0 = wgt + (size_t)oc0 * CIN * 9;
    const float* w1 = w0 + (size_t)CIN * 9;

    for (int c = 0; c < CIN; ++c) {
        const float* xc = xb + c * HW;
        float v[9];
#pragma unroll
        for (int ky = 0; ky < 3; ++ky) {
            const int y = h + ky - 1;
            const bool yok = (unsigned)y < (unsigned)H;
#pragma unroll
            for (int kx = 0; kx < 3; ++kx) {
                const int xx = wcol + kx - 1;
                const bool ok = yok && ((unsigned)xx < (unsigned)W);
                v[ky * 3 + kx] = ok ? xc[y * W + xx] : 0.f;
            }
        }
#pragma unroll
        for (int k = 0; k < 9; ++k) {
            acc0 = fmaf(v[k], w0[c * 9 + k], acc0);
            acc1 = fmaf(v[k], w1[c * 9 + k], acc1);
        }
    }
    out[((size_t)b * 18 + oc0    ) * HW + pix] = acc0 + bias[oc0];
    out[((size_t)b * 18 + oc0 + 1) * HW + pix] = acc1 + bias[oc0 + 1];
}

// ---------------------------------------------------------------------------
// Deformable conv v1: 3x3, stride 1, pad 1, 1 deform group, no bias.
// Block = 256 threads = 16 consecutive pixels of one batch image, all 256 oc.
// Phase 0: bilinear corner idx/wgt per (pixel, tap) -> LDS.
// Then loop over 8 channel-chunks (32 c each):
//   phase 1: cooperative bilinear gather -> smp[16][288] (LDS)
//   phase 2: thread t = out channel; acc[p] += dot(smp[p][.], W[t][.])
// grid: (HW/16, B)
// ---------------------------------------------------------------------------
#define P_   16           // pixels per block
#define CCH  32           // channels per chunk
#define NCH  (CIN / CCH)  // 8
#define CKL  (CCH * 9)    // 288

__global__ __launch_bounds__(256) void deform_conv_k(
    const float* __restrict__ x, const float* __restrict__ offs,
    const float* __restrict__ wgt, float* __restrict__ out,
    int H, int W)
{
    __shared__ float smp[P_][CKL];      // 18.4 KB
    __shared__ int   sidx[P_][9][4];    // 2.3 KB
    __shared__ float swgt[P_][9][4];    // 2.3 KB

    const int HW   = H * W;
    const int b    = blockIdx.y;
    const int pix0 = blockIdx.x * P_;
    const int t    = threadIdx.x;

    // ---- phase 0: sampling parameters --------------------------------------
    if (t < P_ * 9) {
        const int p = t / 9;
        const int k = t - 9 * p;
        const int pix = pix0 + p;
        const int h  = pix / W;
        const int wc = pix - h * W;
        const float* ob = offs + (size_t)b * 18 * HW;
        const float dy = ob[(2 * k    ) * HW + pix];
        const float dx = ob[(2 * k + 1) * HW + pix];
        const float sy = (float)(h  + k / 3 - 1) + dy;
        const float sx = (float)(wc + k % 3 - 1) + dx;
        const float y0f = floorf(sy), x0f = floorf(sx);
        const float ly = sy - y0f, lx = sx - x0f;
        const int y0 = (int)y0f, x0 = (int)x0f;
#pragma unroll
        for (int j = 0; j < 4; ++j) {
            const int yy = y0 + (j >> 1);
            const int xx = x0 + (j & 1);
            const bool ok = ((unsigned)yy < (unsigned)H) && ((unsigned)xx < (unsigned)W);
            const int yc  = min(max(yy, 0), H - 1);
            const int xcl = min(max(xx, 0), W - 1);
            sidx[p][k][j] = yc * W + xcl;
            const float wj = ((j >> 1) ? ly : 1.f - ly) * ((j & 1) ? lx : 1.f - lx);
            swgt[p][k][j] = ok ? wj : 0.f;
        }
    }

    const float* xb = x + (size_t)b * CIN * HW;
    const int o = t;
    float acc[P_];
#pragma unroll
    for (int p = 0; p < P_; ++p) acc[p] = 0.f;

    for (int cc = 0; cc < NCH; ++cc) {
        __syncthreads();   // params ready (cc==0) / phase-2 readers done (cc>0)

        // ---- phase 1: bilinear gather of this channel chunk ---------------
        for (int i = t; i < P_ * CKL; i += 256) {
            const int p   = i / CKL;
            const int ckl = i - p * CKL;
            const int cl  = ckl / 9;
            const int k   = ckl - 9 * cl;
            const float* xc = xb + (cc * CCH + cl) * HW;
            smp[p][ckl] = swgt[p][k][0] * xc[sidx[p][k][0]]
                        + swgt[p][k][1] * xc[sidx[p][k][1]]
                        + swgt[p][k][2] * xc[sidx[p][k][2]]
                        + swgt[p][k][3] * xc[sidx[p][k][3]];
        }
        __syncthreads();

        // ---- phase 2: matvec against this chunk's weights -----------------
        const float4* wrow = (const float4*)(wgt + (size_t)o * (CIN * 9) + cc * CKL);
#pragma unroll 4
        for (int q = 0; q < CKL / 4; ++q) {
            const float4 wv = wrow[q];
#pragma unroll
            for (int p = 0; p < P_; ++p) {
                const float4 s = ((const float4*)smp[p])[q];
                acc[p] = fmaf(s.x, wv.x,
                         fmaf(s.y, wv.y,
                         fmaf(s.z, wv.z,
                         fmaf(s.w, wv.w, acc[p]))));
            }
        }
    }

    float* op = out + ((size_t)b * OC + o) * HW + pix0;
#pragma unroll
    for (int p = 0; p < P_; ++p) op[p] = acc[p];
}

// ---------------------------------------------------------------------------
// Launcher. Input order: kernel, search, Toffset_w, Toffset_b, Tdeform_w,
//                        Soffset_w, Soffset_b, Sdeform_w
// Output order: kernel_out[16,256,16,16], search_out[16,256,32,32],
//               kernel_offset[16,18,16,16], search_offset[16,18,32,32]
// ---------------------------------------------------------------------------
extern "C" void kernel_launch(void* const* d_in, const int* in_sizes, int n_in,
                              void* d_out, int out_size, void* d_ws, size_t ws_size,
                              hipStream_t stream) {
    const float* kin = (const float*)d_in[0];
    const float* sin_ = (const float*)d_in[1];
    const float* tow = (const float*)d_in[2];
    const float* tob = (const float*)d_in[3];
    const float* tdw = (const float*)d_in[4];
    const float* sow = (const float*)d_in[5];
    const float* sob = (const float*)d_in[6];
    const float* sdw = (const float*)d_in[7];

    float* out = (float*)d_out;
    float* out_k  = out;                                      // 16*256*16*16
    float* out_s  = out_k + (size_t)16 * 256 * 16 * 16;       // 16*256*32*32
    float* out_ko = out_s + (size_t)16 * 256 * 32 * 32;       // 16*18*16*16
    float* out_so = out_ko + (size_t)16 * 18 * 16 * 16;       // 16*18*32*32

    // offset convs (write out_ko / out_so, consumed below on the same stream)
    offset_conv_k<<<dim3(1, 9, 16), 256, 0, stream>>>(kin,  tow, tob, out_ko, 16, 16);
    offset_conv_k<<<dim3(4, 9, 16), 256, 0, stream>>>(sin_, sow, sob, out_so, 32, 32);

    // deformable convs
    deform_conv_k<<<dim3(256 / P_, 16), 256, 0, stream>>>(kin,  out_ko, tdw, out_k, 16, 16);
    deform_conv_k<<<dim3(1024 / P_, 16), 256, 0, stream>>>(sin_, out_so, sdw, out_s, 32, 32);
}

// Round 2
// 583.202 us; speedup vs baseline: 1.9489x; 1.9489x over previous
//
#include <hip/hip_runtime.h>

#define CIN   256
#define OC    256
#define K_TOT (CIN * 9)        // 2304
#define CCH   32               // channels per K-chunk
#define NCHK  (CIN / CCH)      // 8
#define KCH   (CCH * 9)        // 288 k-values per chunk
#define SSTR  (KCH + 8)        // 296: 16B-aligned rows, 2-way-max LDS banks

typedef short  bf16x8 __attribute__((ext_vector_type(8)));
typedef float  f32x4  __attribute__((ext_vector_type(4)));
typedef unsigned short ushort_t;

__device__ __forceinline__ ushort_t f2bf(float f) {
    unsigned u = __builtin_bit_cast(unsigned, f);
    u += 0x7fffu + ((u >> 16) & 1u);          // RNE
    return (ushort_t)(u >> 16);
}

// ---------------------------------------------------------------------------
// Weight fp32 -> bf16 converters (into d_ws)
// ---------------------------------------------------------------------------
__global__ __launch_bounds__(256) void cvt_deform_w_k(
    const float* __restrict__ src, ushort_t* __restrict__ dst, int n)
{
    int i = blockIdx.x * 256 + threadIdx.x;
    if (i < n) dst[i] = f2bf(src[i]);
}

// offset weights: [18][2304] -> padded [32][2304], rows 18..31 zero
__global__ __launch_bounds__(256) void cvt_offset_w_k(
    const float* __restrict__ src, ushort_t* __restrict__ dst)
{
    int i = blockIdx.x * 256 + threadIdx.x;   // over 32*2304
    int oc = i / K_TOT;
    dst[i] = (oc < 18) ? f2bf(src[i]) : (ushort_t)0;
}

// ---------------------------------------------------------------------------
// Offset conv as bf16 MFMA GEMM: M=64 pixels/block, N=32 (18 real oc), K=2304.
// Block 256 = 4 waves; wave w owns pixels [w*16, w*16+16), both n-tiles.
// grid: (HW/64, B)
// ---------------------------------------------------------------------------
__global__ __launch_bounds__(256) void conv_gemm_k(
    const float* __restrict__ x, const ushort_t* __restrict__ wgt,
    const float* __restrict__ bias, float* __restrict__ out,
    int H, int W)
{
    __shared__ __align__(16) ushort_t smp[64][SSTR];   // 37.9 KB

    const int HW   = H * W;
    const int b    = blockIdx.y;
    const int pix0 = blockIdx.x * 64;
    const int t    = threadIdx.x;
    const int lane = t & 63;
    const int wv   = t >> 6;
    const int l15  = lane & 15;
    const int acol = (lane >> 4) * 8;

    const float* xb = x + (size_t)b * CIN * HW;

    // im2col geometry for this thread's gather pixel
    const int gp  = t >> 2;           // 0..63  pixel within block
    const int gj  = t & 3;            // channel mod 4
    const int gpix = pix0 + gp;
    const int gh  = gpix / W;
    const int gw  = gpix - gh * W;

    f32x4 acc[2] = {};

    for (int cc = 0; cc < NCHK; ++cc) {
        if (cc) __syncthreads();
        // ---- gather (im2col, zero pad) -> LDS bf16 ------------------------
#pragma unroll
        for (int k = 0; k < 9; ++k) {
            const int y  = gh + k / 3 - 1;
            const int xx = gw + k % 3 - 1;
            const bool ok = ((unsigned)y < (unsigned)H) && ((unsigned)xx < (unsigned)W);
            const int idx = ok ? (y * W + xx) : 0;
#pragma unroll
            for (int cq = 0; cq < 8; ++cq) {
                const int cl = cq * 4 + gj;
                const float v = ok ? xb[(cc * CCH + cl) * HW + idx] : 0.f;
                smp[gp][cl * 9 + k] = f2bf(v);
            }
        }
        __syncthreads();
        // ---- MFMA: 9 K-steps of 32 ---------------------------------------
#pragma unroll
        for (int ks = 0; ks < 9; ++ks) {
            bf16x8 a = *(const bf16x8*)&smp[wv * 16 + l15][ks * 32 + acol];
            const size_t kg = (size_t)cc * KCH + ks * 32 + acol;
#pragma unroll
            for (int nt = 0; nt < 2; ++nt) {
                bf16x8 bb = *(const bf16x8*)&wgt[(size_t)(nt * 16 + l15) * K_TOT + kg];
                acc[nt] = __builtin_amdgcn_mfma_f32_16x16x32_bf16(a, bb, acc[nt], 0, 0, 0);
            }
        }
    }

    // ---- epilogue: bias, store oc<18 --------------------------------------
    const int prow = (lane >> 4) * 4;
#pragma unroll
    for (int nt = 0; nt < 2; ++nt) {
        const int oc = nt * 16 + l15;
        if (oc < 18) {
            const float bs = bias[oc];
            float4 r = { acc[nt].x + bs, acc[nt].y + bs, acc[nt].z + bs, acc[nt].w + bs };
            *(float4*)(out + ((size_t)b * 18 + oc) * HW + pix0 + wv * 16 + prow) = r;
        }
    }
}

// ---------------------------------------------------------------------------
// Deformable conv as bf16 MFMA GEMM: M=32 pixels/block, N=256, K=2304.
// Block 256 = 4 waves; wave w owns oc [w*64, w*64+64) (4 n-tiles), 2 m-tiles.
// grid: (HW/32, B)
// ---------------------------------------------------------------------------
__global__ __launch_bounds__(256) void deform_gemm_k(
    const float* __restrict__ x, const float* __restrict__ offs,
    const ushort_t* __restrict__ wgt, float* __restrict__ out,
    int H, int W)
{
    __shared__ __align__(16) ushort_t smp[32][SSTR];     // 18.9 KB
    __shared__ __align__(16) int      sidx[32][9][4];    // 4.6 KB
    __shared__ __align__(16) float    swgt[32][9][4];    // 4.6 KB

    const int HW   = H * W;
    const int b    = blockIdx.y;
    const int pix0 = blockIdx.x * 32;
    const int t    = threadIdx.x;
    const int lane = t & 63;
    const int wv   = t >> 6;
    const int l15  = lane & 15;
    const int acol = (lane >> 4) * 8;

    // ---- phase 0: bilinear sampling params (32 pix x 9 taps) --------------
    for (int i = t; i < 32 * 9; i += 256) {
        const int p = i / 9, k = i - 9 * p;
        const int pix = pix0 + p;
        const int h  = pix / W;
        const int wc = pix - h * W;
        const float* ob = offs + (size_t)b * 18 * HW;
        const float dy = ob[(2 * k    ) * HW + pix];
        const float dx = ob[(2 * k + 1) * HW + pix];
        const float sy = (float)(h  + k / 3 - 1) + dy;
        const float sx = (float)(wc + k % 3 - 1) + dx;
        const float y0f = floorf(sy), x0f = floorf(sx);
        const float ly = sy - y0f, lx = sx - x0f;
        const int y0 = (int)y0f, x0 = (int)x0f;
#pragma unroll
        for (int j = 0; j < 4; ++j) {
            const int yy = y0 + (j >> 1);
            const int xx = x0 + (j & 1);
            const bool ok = ((unsigned)yy < (unsigned)H) && ((unsigned)xx < (unsigned)W);
            sidx[p][k][j] = min(max(yy, 0), H - 1) * W + min(max(xx, 0), W - 1);
            const float wj = ((j >> 1) ? ly : 1.f - ly) * ((j & 1) ? lx : 1.f - lx);
            swgt[p][k][j] = ok ? wj : 0.f;
        }
    }
    __syncthreads();

    const float* xb = x + (size_t)b * CIN * HW;
    const int gp = t >> 3;      // gather pixel 0..31
    const int gj = t & 7;       // channel mod 8

    f32x4 acc[2][4] = {};

    for (int cc = 0; cc < NCHK; ++cc) {
        if (cc) __syncthreads();
        // ---- phase 1: bilinear gather -> LDS bf16 -------------------------
#pragma unroll
        for (int k = 0; k < 9; ++k) {
            const int4   id = *(const int4*)  sidx[gp][k];
            const float4 wt = *(const float4*)swgt[gp][k];
#pragma unroll
            for (int cq = 0; cq < 4; ++cq) {
                const int cl = cq * 8 + gj;
                const float* xc = xb + (cc * CCH + cl) * HW;
                const float v = wt.x * xc[id.x] + wt.y * xc[id.y]
                              + wt.z * xc[id.z] + wt.w * xc[id.w];
                smp[gp][cl * 9 + k] = f2bf(v);
            }
        }
        __syncthreads();
        // ---- phase 2: MFMA, 9 K-steps of 32 -------------------------------
#pragma unroll
        for (int ks = 0; ks < 9; ++ks) {
            bf16x8 a0 = *(const bf16x8*)&smp[l15     ][ks * 32 + acol];
            bf16x8 a1 = *(const bf16x8*)&smp[16 + l15][ks * 32 + acol];
            const size_t kg = (size_t)cc * KCH + ks * 32 + acol;
#pragma unroll
            for (int nt = 0; nt < 4; ++nt) {
                const int oc = wv * 64 + nt * 16 + l15;
                bf16x8 bb = *(const bf16x8*)&wgt[(size_t)oc * K_TOT + kg];
                acc[0][nt] = __builtin_amdgcn_mfma_f32_16x16x32_bf16(a0, bb, acc[0][nt], 0, 0, 0);
                acc[1][nt] = __builtin_amdgcn_mfma_f32_16x16x32_bf16(a1, bb, acc[1][nt], 0, 0, 0);
            }
        }
    }

    // ---- epilogue ---------------------------------------------------------
    const int prow = (lane >> 4) * 4;
#pragma unroll
    for (int mt = 0; mt < 2; ++mt) {
#pragma unroll
        for (int nt = 0; nt < 4; ++nt) {
            const int oc = wv * 64 + nt * 16 + l15;
            float* op = out + ((size_t)b * OC + oc) * HW + pix0 + mt * 16 + prow;
            *(float4*)op = *(float4*)&acc[mt][nt];
        }
    }
}

// ---------------------------------------------------------------------------
// Launcher. Inputs: kernel, search, Toffset_w, Toffset_b, Tdeform_w,
//                   Soffset_w, Soffset_b, Sdeform_w
// Outputs: kernel_out[16,256,16,16], search_out[16,256,32,32],
//          kernel_offset[16,18,16,16], search_offset[16,18,32,32]
// ---------------------------------------------------------------------------
extern "C" void kernel_launch(void* const* d_in, const int* in_sizes, int n_in,
                              void* d_out, int out_size, void* d_ws, size_t ws_size,
                              hipStream_t stream) {
    const float* kin = (const float*)d_in[0];
    const float* sin_ = (const float*)d_in[1];
    const float* tow = (const float*)d_in[2];
    const float* tob = (const float*)d_in[3];
    const float* tdw = (const float*)d_in[4];
    const float* sow = (const float*)d_in[5];
    const float* sob = (const float*)d_in[6];
    const float* sdw = (const float*)d_in[7];

    float* out = (float*)d_out;
    float* out_k  = out;                                      // 16*256*16*16
    float* out_s  = out_k + (size_t)16 * 256 * 16 * 16;       // 16*256*32*32
    float* out_ko = out_s + (size_t)16 * 256 * 32 * 32;       // 16*18*16*16
    float* out_so = out_ko + (size_t)16 * 18 * 16 * 16;       // 16*18*32*32

    // bf16 weight staging in d_ws (needs 2.66 MB)
    const int nDW = OC * K_TOT;        // 589824
    const int nOW = 32 * K_TOT;        // 73728 (padded)
    ushort_t* wk_d = (ushort_t*)d_ws;
    ushort_t* ws_d = wk_d + nDW;
    ushort_t* wk_o = ws_d + nDW;
    ushort_t* ws_o = wk_o + nOW;

    cvt_deform_w_k<<<dim3((nDW + 255) / 256), 256, 0, stream>>>(tdw, wk_d, nDW);
    cvt_deform_w_k<<<dim3((nDW + 255) / 256), 256, 0, stream>>>(sdw, ws_d, nDW);
    cvt_offset_w_k<<<dim3(nOW / 256), 256, 0, stream>>>(tow, wk_o);
    cvt_offset_w_k<<<dim3(nOW / 256), 256, 0, stream>>>(sow, ws_o);

    // offset convs (M=64/block)
    conv_gemm_k<<<dim3(256 / 64, 16), 256, 0, stream>>>(kin,  wk_o, tob, out_ko, 16, 16);
    conv_gemm_k<<<dim3(1024 / 64, 16), 256, 0, stream>>>(sin_, ws_o, sob, out_so, 32, 32);

    // deformable convs (M=32/block)
    deform_gemm_k<<<dim3(256 / 32, 16), 256, 0, stream>>>(kin,  out_ko, wk_d, out_k, 16, 16);
    deform_gemm_k<<<dim3(1024 / 32, 16), 256, 0, stream>>>(sin_, out_so, ws_d, out_s, 32, 32);
}

// Round 3
// 476.913 us; speedup vs baseline: 2.3832x; 1.2229x over previous
//
#include <hip/hip_runtime.h>

#define CIN   256
#define OC    256
#define K_TOT (CIN * 9)        // 2304
#define CCH   32               // channels per K-chunk
#define NCHK  (CIN / CCH)      // 8
#define KCH   (CCH * 9)        // 288 k-values per chunk
#define SSTR  (KCH + 8)        // 296: 16B-aligned rows, 2-way-max LDS banks

#define N_DW  (OC * K_TOT)     // deform weight elements
#define N_OW  (32 * K_TOT)     // padded offset weight elements

typedef short  bf16x8 __attribute__((ext_vector_type(8)));
typedef float  f32x4  __attribute__((ext_vector_type(4)));
typedef unsigned short ushort_t;

__device__ __forceinline__ ushort_t f2bf(float f) {
    unsigned u = __builtin_bit_cast(unsigned, f);
    u += 0x7fffu + ((u >> 16) & 1u);          // RNE
    return (ushort_t)(u >> 16);
}

// ---------------------------------------------------------------------------
// One cvt kernel for all four weight tensors (fp32 -> bf16 into d_ws).
// Segments: [0,N_DW) tdw -> wk_d ; [N_DW,2N_DW) sdw -> ws_d ;
//           then N_OW kernel-offset (pad oc>=18 with 0), then N_OW search.
// ---------------------------------------------------------------------------
__global__ __launch_bounds__(256) void cvt_all_k(
    const float* __restrict__ tdw, const float* __restrict__ sdw,
    const float* __restrict__ tow, const float* __restrict__ sow,
    ushort_t* __restrict__ wk_d, ushort_t* __restrict__ ws_d,
    ushort_t* __restrict__ wk_o, ushort_t* __restrict__ ws_o)
{
    int i = blockIdx.x * 256 + threadIdx.x;
    if (i < N_DW) {
        wk_d[i] = f2bf(tdw[i]);
    } else if (i < 2 * N_DW) {
        int j = i - N_DW;
        ws_d[j] = f2bf(sdw[j]);
    } else if (i < 2 * N_DW + N_OW) {
        int j = i - 2 * N_DW;
        wk_o[j] = (j / K_TOT < 18) ? f2bf(tow[j]) : (ushort_t)0;
    } else if (i < 2 * N_DW + 2 * N_OW) {
        int j = i - 2 * N_DW - N_OW;
        ws_o[j] = (j / K_TOT < 18) ? f2bf(sow[j]) : (ushort_t)0;
    }
}

// ---------------------------------------------------------------------------
// Offset conv as bf16 MFMA GEMM: M=64 px/block, N=32 (18 real oc), K=2304.
// Both branches in one launch: blockIdx.x < 64 -> kernel (16x16), else search.
// ---------------------------------------------------------------------------
__global__ __launch_bounds__(256) void conv_gemm_k(
    const float* __restrict__ kin, const ushort_t* __restrict__ kwgt,
    const float* __restrict__ kbias, float* __restrict__ kout,
    const float* __restrict__ sin_, const ushort_t* __restrict__ swgt,
    const float* __restrict__ sbias, float* __restrict__ sout)
{
    __shared__ __align__(16) ushort_t smp[64][SSTR];   // 37.9 KB

    int H, W, b, pix0;
    const float* x; const ushort_t* wgt; const float* bias; float* out;
    if (blockIdx.x < 64) {            // kernel branch: 4096 px / 64 = 64 tiles
        H = 16; W = 16; x = kin;  wgt = kwgt; bias = kbias; out = kout;
        b = blockIdx.x >> 2; pix0 = (blockIdx.x & 3) * 64;
    } else {                          // search branch: 16384 px / 64 = 256 tiles
        int t2 = blockIdx.x - 64;
        H = 32; W = 32; x = sin_; wgt = swgt; bias = sbias; out = sout;
        b = t2 >> 4; pix0 = (t2 & 15) * 64;
    }
    const int HW = H * W;

    const int t    = threadIdx.x;
    const int lane = t & 63;
    const int wv   = t >> 6;
    const int l15  = lane & 15;
    const int acol = (lane >> 4) * 8;

    const float* xb = x + (size_t)b * CIN * HW;

    // gather mapping: lane = pixel (coalesced within a channel plane)
    const int gp   = lane;            // 0..63 pixel within block
    const int gpix = pix0 + gp;
    const int gh   = gpix / W;
    const int gw   = gpix - gh * W;

    f32x4 acc[2] = {};

    for (int cc = 0; cc < NCHK; ++cc) {
        if (cc) __syncthreads();
        // ---- im2col gather -> LDS bf16; per instr: 1 channel x 64 px ------
#pragma unroll
        for (int k = 0; k < 9; ++k) {
            const int y  = gh + k / 3 - 1;
            const int xx = gw + k % 3 - 1;
            const bool ok = ((unsigned)y < (unsigned)H) && ((unsigned)xx < (unsigned)W);
            const int idx = ok ? (y * W + xx) : 0;
#pragma unroll
            for (int ci = 0; ci < 8; ++ci) {
                const int cl = ci * 4 + wv;
                const float v = ok ? xb[(cc * CCH + cl) * HW + idx] : 0.f;
                smp[gp][cl * 9 + k] = f2bf(v);
            }
        }
        __syncthreads();
        // ---- MFMA: 9 K-steps of 32 ---------------------------------------
#pragma unroll
        for (int ks = 0; ks < 9; ++ks) {
            bf16x8 a = *(const bf16x8*)&smp[wv * 16 + l15][ks * 32 + acol];
            const size_t kg = (size_t)cc * KCH + ks * 32 + acol;
#pragma unroll
            for (int nt = 0; nt < 2; ++nt) {
                bf16x8 bb = *(const bf16x8*)&wgt[(size_t)(nt * 16 + l15) * K_TOT + kg];
                acc[nt] = __builtin_amdgcn_mfma_f32_16x16x32_bf16(a, bb, acc[nt], 0, 0, 0);
            }
        }
    }

    // ---- epilogue: bias, store oc<18 --------------------------------------
    const int prow = (lane >> 4) * 4;
#pragma unroll
    for (int nt = 0; nt < 2; ++nt) {
        const int oc = nt * 16 + l15;
        if (oc < 18) {
            const float bs = bias[oc];
            float4 r = { acc[nt].x + bs, acc[nt].y + bs, acc[nt].z + bs, acc[nt].w + bs };
            *(float4*)(out + ((size_t)b * 18 + oc) * HW + pix0 + wv * 16 + prow) = r;
        }
    }
}

// ---------------------------------------------------------------------------
// Deformable conv as bf16 MFMA GEMM: M=32 px/block, N=256, K=2304.
// Block 256 = 4 waves; wave w: m-tile (w&1), oc range [(w>>1)*128, +128).
// Gather lanes: 32 px x 2 channel planes -> ~4-12 cache lines / instr.
// Both branches in one launch: blockIdx.x < 128 -> kernel, else search.
// ---------------------------------------------------------------------------
__global__ __launch_bounds__(256, 2) void deform_gemm_k(
    const float* __restrict__ kin, const float* __restrict__ koffs,
    const ushort_t* __restrict__ kwgt, float* __restrict__ kout,
    const float* __restrict__ sin_, const float* __restrict__ soffs,
    const ushort_t* __restrict__ swgt_, float* __restrict__ sout)
{
    __shared__ __align__(16) ushort_t smp[32][SSTR];     // 18.9 KB
    __shared__ __align__(16) int      sidx[32][9][4];    // 4.6 KB
    __shared__ __align__(16) float    swt [32][9][4];    // 4.6 KB

    int H, W, b, pix0;
    const float* x; const float* offs; const ushort_t* wgt; float* out;
    if (blockIdx.x < 128) {           // kernel: 4096 px / 32 = 128 tiles
        H = 16; W = 16; x = kin;  offs = koffs; wgt = kwgt;  out = kout;
        b = blockIdx.x >> 3; pix0 = (blockIdx.x & 7) * 32;
    } else {                          // search: 16384 px / 32 = 512 tiles
        int t2 = blockIdx.x - 128;
        H = 32; W = 32; x = sin_; offs = soffs; wgt = swgt_; out = sout;
        b = t2 >> 5; pix0 = (t2 & 31) * 32;
    }
    const int HW = H * W;

    const int t    = threadIdx.x;
    const int lane = t & 63;
    const int wv   = t >> 6;

    // ---- phase 0: bilinear sampling params (32 px x 9 taps) --------------
    for (int i = t; i < 32 * 9; i += 256) {
        const int p = i / 9, k = i - 9 * p;
        const int pix = pix0 + p;
        const int h  = pix / W;
        const int wc = pix - h * W;
        const float* ob = offs + (size_t)b * 18 * HW;
        const float dy = ob[(2 * k    ) * HW + pix];
        const float dx = ob[(2 * k + 1) * HW + pix];
        const float sy = (float)(h  + k / 3 - 1) + dy;
        const float sx = (float)(wc + k % 3 - 1) + dx;
        const float y0f = floorf(sy), x0f = floorf(sx);
        const float ly = sy - y0f, lx = sx - x0f;
        const int y0 = (int)y0f, x0 = (int)x0f;
#pragma unroll
        for (int j = 0; j < 4; ++j) {
            const int yy = y0 + (j >> 1);
            const int xx = x0 + (j & 1);
            const bool ok = ((unsigned)yy < (unsigned)H) && ((unsigned)xx < (unsigned)W);
            sidx[p][k][j] = min(max(yy, 0), H - 1) * W + min(max(xx, 0), W - 1);
            const float wj = ((j >> 1) ? ly : 1.f - ly) * ((j & 1) ? lx : 1.f - lx);
            swt[p][k][j] = ok ? wj : 0.f;
        }
    }
    __syncthreads();

    const float* xb  = x + (size_t)b * CIN * HW;
    const int gp  = lane & 31;        // gather pixel
    const int gh2 = lane >> 5;        // channel half (2 planes per instr)

    const int l15  = lane & 15;
    const int acol = (lane >> 4) * 8;
    const int mt   = wv & 1;          // m-tile of this wave
    const int nb   = (wv >> 1) * 128; // oc base of this wave

    f32x4 acc[8] = {};

    for (int cc = 0; cc < NCHK; ++cc) {
        if (cc) __syncthreads();
        // ---- phase 1: bilinear gather -> LDS bf16 -------------------------
        // k outer so sidx/swt are read once per tap; ci inner = 4 independent
        // channel planes of scheduled loads.
#pragma unroll
        for (int k = 0; k < 9; ++k) {
            const int4   id = *(const int4*)  sidx[gp][k];
            const float4 wt = *(const float4*)swt [gp][k];
#pragma unroll
            for (int ci = 0; ci < 4; ++ci) {
                const int cl = ci * 8 + wv * 2 + gh2;
                const float* xc = xb + (cc * CCH + cl) * HW;
                const float v = wt.x * xc[id.x] + wt.y * xc[id.y]
                              + wt.z * xc[id.z] + wt.w * xc[id.w];
                smp[gp][cl * 9 + k] = f2bf(v);
            }
        }
        __syncthreads();
        // ---- phase 2: MFMA, 9 K-steps of 32 -------------------------------
#pragma unroll
        for (int ks = 0; ks < 9; ++ks) {
            bf16x8 a = *(const bf16x8*)&smp[mt * 16 + l15][ks * 32 + acol];
            const size_t kg = (size_t)cc * KCH + ks * 32 + acol;
#pragma unroll
            for (int nt = 0; nt < 8; ++nt) {
                const int oc = nb + nt * 16 + l15;
                bf16x8 bb = *(const bf16x8*)&wgt[(size_t)oc * K_TOT + kg];
                acc[nt] = __builtin_amdgcn_mfma_f32_16x16x32_bf16(a, bb, acc[nt], 0, 0, 0);
            }
        }
    }

    // ---- epilogue ---------------------------------------------------------
    const int prow = (lane >> 4) * 4;
#pragma unroll
    for (int nt = 0; nt < 8; ++nt) {
        const int oc = nb + nt * 16 + l15;
        float* op = out + ((size_t)b * OC + oc) * HW + pix0 + mt * 16 + prow;
        *(float4*)op = *(float4*)&acc[nt];
    }
}

// ---------------------------------------------------------------------------
// Launcher. Inputs: kernel, search, Toffset_w, Toffset_b, Tdeform_w,
//                   Soffset_w, Soffset_b, Sdeform_w
// Outputs: kernel_out[16,256,16,16], search_out[16,256,32,32],
//          kernel_offset[16,18,16,16], search_offset[16,18,32,32]
// ---------------------------------------------------------------------------
extern "C" void kernel_launch(void* const* d_in, const int* in_sizes, int n_in,
                              void* d_out, int out_size, void* d_ws, size_t ws_size,
                              hipStream_t stream) {
    const float* kin = (const float*)d_in[0];
    const float* sin_ = (const float*)d_in[1];
    const float* tow = (const float*)d_in[2];
    const float* tob = (const float*)d_in[3];
    const float* tdw = (const float*)d_in[4];
    const float* sow = (const float*)d_in[5];
    const float* sob = (const float*)d_in[6];
    const float* sdw = (const float*)d_in[7];

    float* out = (float*)d_out;
    float* out_k  = out;                                      // 16*256*16*16
    float* out_s  = out_k + (size_t)16 * 256 * 16 * 16;       // 16*256*32*32
    float* out_ko = out_s + (size_t)16 * 256 * 32 * 32;       // 16*18*16*16
    float* out_so = out_ko + (size_t)16 * 18 * 16 * 16;       // 16*18*32*32

    // bf16 weight staging in d_ws (2.66 MB)
    ushort_t* wk_d = (ushort_t*)d_ws;
    ushort_t* ws_d = wk_d + N_DW;
    ushort_t* wk_o = ws_d + N_DW;
    ushort_t* ws_o = wk_o + N_OW;

    const int n_cvt = 2 * N_DW + 2 * N_OW;
    cvt_all_k<<<dim3((n_cvt + 255) / 256), 256, 0, stream>>>(
        tdw, sdw, tow, sow, wk_d, ws_d, wk_o, ws_o);

    // offset convs, both branches (64 + 256 tiles)
    conv_gemm_k<<<dim3(320), 256, 0, stream>>>(
        kin, wk_o, tob, out_ko, sin_, ws_o, sob, out_so);

    // deformable convs, both branches (128 + 512 tiles)
    deform_gemm_k<<<dim3(640), 256, 0, stream>>>(
        kin, out_ko, wk_d, out_k, sin_, out_so, ws_d, out_s);
}

// Round 4
// 261.958 us; speedup vs baseline: 4.3388x; 1.8206x over previous
//
#include <hip/hip_runtime.h>

#define CIN   256
#define OC    256
#define K_TOT 2304             // 256*9
#define CCH   32               // channels per K-chunk
#define NCHK  8                // K chunks
#define KCH   288              // k-values per chunk (tap-major: k = tap*32 + c)
#define SSTR  296              // LDS row stride (bf16 elems), 16B-aligned, padded

#define N_DW  (OC * K_TOT)     // deform weight elements (589824)
#define N_OW  (32 * K_TOT)     // padded offset weight elements (73728)

typedef short  bf16x8 __attribute__((ext_vector_type(8)));
typedef float  f32x4  __attribute__((ext_vector_type(4)));
typedef unsigned short ushort_t;

__device__ __forceinline__ ushort_t f2bf(float f) {
    unsigned u = __builtin_bit_cast(unsigned, f);
    u += 0x7fffu + ((u >> 16) & 1u);          // RNE
    return (ushort_t)(u >> 16);
}
__device__ __forceinline__ float bf2f(short s) {
    return __builtin_bit_cast(float, ((unsigned)(unsigned short)s) << 16);
}

// ---------------------------------------------------------------------------
// Weight cvt fp32->bf16 WITH K-permutation to tap-major:
//   dst[oc][cc][tap][cl] = src[oc][cc*32+cl][tap]
// Segments: N_DW tdw, N_DW sdw, N_OW tow (zero-pad oc>=18), N_OW sow.
// ---------------------------------------------------------------------------
__global__ __launch_bounds__(256) void cvt_w_k(
    const float* __restrict__ tdw, const float* __restrict__ sdw,
    const float* __restrict__ tow, const float* __restrict__ sow,
    ushort_t* __restrict__ wk_d, ushort_t* __restrict__ ws_d,
    ushort_t* __restrict__ wk_o, ushort_t* __restrict__ ws_o)
{
    int i = blockIdx.x * 256 + threadIdx.x;
    const float* src; ushort_t* dst; int j; bool offw = false;
    if (i < N_DW)                   { src = tdw; dst = wk_d; j = i; }
    else if (i < 2 * N_DW)          { src = sdw; dst = ws_d; j = i - N_DW; }
    else if (i < 2 * N_DW + N_OW)   { src = tow; dst = wk_o; j = i - 2 * N_DW; offw = true; }
    else if (i < 2 * N_DW + 2 * N_OW){ src = sow; dst = ws_o; j = i - 2 * N_DW - N_OW; offw = true; }
    else return;
    const int oc = j / K_TOT;
    const int k  = j - oc * K_TOT;
    const int cc = k / KCH;
    const int r  = k - cc * KCH;
    const int tap = r >> 5;
    const int cl  = r & 31;
    float v = 0.f;
    if (!offw || oc < 18) v = src[((size_t)oc * CIN + cc * 32 + cl) * 9 + tap];
    dst[j] = f2bf(v);
}

// ---------------------------------------------------------------------------
// Input transpose NCHW fp32 -> HWC bf16 (xt[b][px][c], c contiguous).
// Block = 64 px of one image. blockIdx.x < 64 -> kernel branch, else search.
// ---------------------------------------------------------------------------
__global__ __launch_bounds__(256) void transpose_k(
    const float* __restrict__ kin, const float* __restrict__ sin_,
    ushort_t* __restrict__ xt_k, ushort_t* __restrict__ xt_s)
{
    __shared__ ushort_t tile[64][264];    // [px][ch], stride 264 (16B-mult)

    int H, W, b, px0; const float* x; ushort_t* xt;
    if (blockIdx.x < 64) {                // kernel: 16 b * 4 tiles
        H = 16; W = 16; x = kin; xt = xt_k;
        b = blockIdx.x >> 2; px0 = (blockIdx.x & 3) * 64;
    } else {                              // search: 16 b * 16 tiles
        int t2 = blockIdx.x - 64;
        H = 32; W = 32; x = sin_; xt = xt_s;
        b = t2 >> 4; px0 = (t2 & 15) * 64;
    }
    const int HW = H * W;
    const int t = threadIdx.x, lane = t & 63, wv = t >> 6;
    const float* xb = x + (size_t)b * CIN * HW;

    // read: wave w -> channels [w*64, w*64+64), 4 ch x 16 px-quads per instr
    for (int it = 0; it < 16; ++it) {
        const int ch = wv * 64 + it * 4 + (lane >> 4);
        const int pq = (lane & 15) * 4;
        float4 v = *(const float4*)&xb[(size_t)ch * HW + px0 + pq];
        tile[pq + 0][ch] = f2bf(v.x);
        tile[pq + 1][ch] = f2bf(v.y);
        tile[pq + 2][ch] = f2bf(v.z);
        tile[pq + 3][ch] = f2bf(v.w);
    }
    __syncthreads();
    // write: 2 px rows per instr (512 B each), coalesced
    for (int it = 0; it < 8; ++it) {
        const int px = it * 8 + wv * 2 + (lane >> 5);
        const int cg = (lane & 31) * 8;
        bf16x8 v = *(const bf16x8*)&tile[px][cg];
        *(bf16x8*)&xt[((size_t)b * HW + px0 + px) * 256 + cg] = v;
    }
}

// ---------------------------------------------------------------------------
// Offset conv as bf16 MFMA GEMM from HWC input. M=64 px/block (4 waves x 16),
// N=32 (18 real oc), K=2304 tap-major. A-frags loaded straight from HWC
// global memory into registers -- no LDS, no barriers.
// blockIdx.x < 64 -> kernel branch, else search.
// ---------------------------------------------------------------------------
__global__ __launch_bounds__(256) void conv_gemm_k(
    const ushort_t* __restrict__ xt_k, const ushort_t* __restrict__ kwgt,
    const float* __restrict__ kbias, float* __restrict__ kout,
    const ushort_t* __restrict__ xt_s, const ushort_t* __restrict__ swgt,
    const float* __restrict__ sbias, float* __restrict__ sout)
{
    int H, W, b, px0;
    const ushort_t* xt; const ushort_t* wgt; const float* bias; float* out;
    if (blockIdx.x < 64) {
        H = 16; W = 16; xt = xt_k; wgt = kwgt; bias = kbias; out = kout;
        b = blockIdx.x >> 2; px0 = (blockIdx.x & 3) * 64;
    } else {
        int t2 = blockIdx.x - 64;
        H = 32; W = 32; xt = xt_s; wgt = swgt; bias = sbias; out = sout;
        b = t2 >> 4; px0 = (t2 & 15) * 64;
    }
    const int HW = H * W;
    const int t = threadIdx.x, lane = t & 63, wv = t >> 6;
    const int l15 = lane & 15;
    const int cg8 = (lane >> 4) * 8;      // k-subgroup = channel subgroup

    const int px = px0 + wv * 16 + l15;   // this lane's A row (m)
    const int h  = px / W;
    const int wc = px - h * W;
    const ushort_t* xtb = xt + (size_t)b * HW * 256;

    f32x4 acc[2] = {};

    for (int cc = 0; cc < NCHK; ++cc) {
#pragma unroll
        for (int ks = 0; ks < 9; ++ks) {          // ks == tap (tap-major K)
            const int y  = h + ks / 3 - 1;
            const int xx = wc + ks % 3 - 1;
            const bool ok = ((unsigned)y < (unsigned)H) && ((unsigned)xx < (unsigned)W);
            bf16x8 a = {};
            if (ok) a = *(const bf16x8*)&xtb[(size_t)(y * W + xx) * 256 + cc * 32 + cg8];
            const size_t kg = (size_t)cc * KCH + ks * 32 + cg8;
#pragma unroll
            for (int nt = 0; nt < 2; ++nt) {
                bf16x8 bb = *(const bf16x8*)&wgt[(size_t)(nt * 16 + l15) * K_TOT + kg];
                acc[nt] = __builtin_amdgcn_mfma_f32_16x16x32_bf16(a, bb, acc[nt], 0, 0, 0);
            }
        }
    }

    const int prow = (lane >> 4) * 4;
#pragma unroll
    for (int nt = 0; nt < 2; ++nt) {
        const int oc = nt * 16 + l15;
        if (oc < 18) {
            const float bs = bias[oc];
            float4 r = { acc[nt].x + bs, acc[nt].y + bs, acc[nt].z + bs, acc[nt].w + bs };
            *(float4*)(out + ((size_t)b * 18 + oc) * HW + px0 + wv * 16 + prow) = r;
        }
    }
}

// ---------------------------------------------------------------------------
// Deformable conv as bf16 MFMA GEMM from HWC input. M=32, N=256, K=2304
// (tap-major). Wave w = oc quarter [w*64,+64), both m-tiles (no B dup).
// Gather: one bf16x8 per (px,tap,corner,ch-group) -- 8 channels per lane.
// blockIdx.x < 256 -> kernel branch, else search.
// ---------------------------------------------------------------------------
__global__ __launch_bounds__(256, 2) void deform_gemm_k(
    const ushort_t* __restrict__ xt_k, const float* __restrict__ koffs,
    const ushort_t* __restrict__ kwgt, float* __restrict__ kout,
    const ushort_t* __restrict__ xt_s, const float* __restrict__ soffs,
    const ushort_t* __restrict__ swgt_, float* __restrict__ sout)
{
    __shared__ __align__(16) ushort_t smp[32][SSTR];     // 18.9 KB
    __shared__ __align__(16) int      sidx[32][9][4];    // 4.6 KB
    __shared__ __align__(16) float    swt [32][9][4];    // 4.6 KB

    int H, W, b, px0;
    const ushort_t* xt; const float* offs; const ushort_t* wgt; float* out;
    if (blockIdx.x < 256) {               // kernel: 16 b * 8 tiles
        H = 16; W = 16; xt = xt_k; offs = koffs; wgt = kwgt; out = kout;
        b = blockIdx.x >> 3; px0 = (blockIdx.x & 7) * 32;
    } else {                              // search: 16 b * 32 tiles
        int t2 = blockIdx.x - 256;
        H = 32; W = 32; xt = xt_s; offs = soffs; wgt = swgt_; out = sout;
        b = t2 >> 5; px0 = (t2 & 31) * 32;
    }
    const int HW = H * W;
    const int t = threadIdx.x, lane = t & 63, wv = t >> 6;

    // ---- phase 0: bilinear params for 32 px x 9 taps ----------------------
    for (int i = t; i < 32 * 9; i += 256) {
        const int p = i / 9, k = i - 9 * p;
        const int pix = px0 + p;
        const int h  = pix / W;
        const int wc = pix - h * W;
        const float* ob = offs + (size_t)b * 18 * HW;
        const float dy = ob[(2 * k    ) * HW + pix];
        const float dx = ob[(2 * k + 1) * HW + pix];
        const float sy = (float)(h  + k / 3 - 1) + dy;
        const float sx = (float)(wc + k % 3 - 1) + dx;
        const float y0f = floorf(sy), x0f = floorf(sx);
        const float ly = sy - y0f, lx = sx - x0f;
        const int y0 = (int)y0f, x0 = (int)x0f;
#pragma unroll
        for (int j = 0; j < 4; ++j) {
            const int yy = y0 + (j >> 1);
            const int xx = x0 + (j & 1);
            const bool ok = ((unsigned)yy < (unsigned)H) && ((unsigned)xx < (unsigned)W);
            sidx[p][k][j] = min(max(yy, 0), H - 1) * W + min(max(xx, 0), W - 1);
            const float wj = ((j >> 1) ? ly : 1.f - ly) * ((j & 1) ? lx : 1.f - lx);
            swt[p][k][j] = ok ? wj : 0.f;
        }
    }
    __syncthreads();

    const ushort_t* xtb = xt + (size_t)b * HW * 256;
    const int l15  = lane & 15;
    const int cg8  = (lane >> 4) * 8;

    f32x4 acc[2][4] = {};

    for (int cc = 0; cc < NCHK; ++cc) {
        if (cc) __syncthreads();
        // ---- phase 1: HWC bilinear gather -> smp (tap-major K) ------------
        // unit s = tap*128 + px*4 + cg : one bf16x8 (8 ch) per corner.
        for (int s = t; s < 1152; s += 256) {
            const int tap = s >> 7;
            const int rr  = s & 127;
            const int px  = rr >> 2;
            const int cg  = rr & 3;
            const int4   id = *(const int4*)  sidx[px][tap];
            const float4 wt = *(const float4*)swt [px][tap];
            const int cb = cc * CCH + cg * 8;
            bf16x8 c0 = *(const bf16x8*)&xtb[(size_t)id.x * 256 + cb];
            bf16x8 c1 = *(const bf16x8*)&xtb[(size_t)id.y * 256 + cb];
            bf16x8 c2 = *(const bf16x8*)&xtb[(size_t)id.z * 256 + cb];
            bf16x8 c3 = *(const bf16x8*)&xtb[(size_t)id.w * 256 + cb];
            bf16x8 r;
#pragma unroll
            for (int j = 0; j < 8; ++j) {
                const float v = wt.x * bf2f(c0[j]) + wt.y * bf2f(c1[j])
                              + wt.z * bf2f(c2[j]) + wt.w * bf2f(c3[j]);
                r[j] = (short)f2bf(v);
            }
            *(bf16x8*)&smp[px][tap * 32 + cg * 8] = r;
        }
        __syncthreads();
        // ---- phase 2: MFMA, 9 K-steps of 32 -------------------------------
#pragma unroll
        for (int ks = 0; ks < 9; ++ks) {
            bf16x8 a0 = *(const bf16x8*)&smp[l15     ][ks * 32 + cg8];
            bf16x8 a1 = *(const bf16x8*)&smp[16 + l15][ks * 32 + cg8];
            const size_t kg = (size_t)cc * KCH + ks * 32 + cg8;
#pragma unroll
            for (int nt = 0; nt < 4; ++nt) {
                const int oc = wv * 64 + nt * 16 + l15;
                bf16x8 bb = *(const bf16x8*)&wgt[(size_t)oc * K_TOT + kg];
                acc[0][nt] = __builtin_amdgcn_mfma_f32_16x16x32_bf16(a0, bb, acc[0][nt], 0, 0, 0);
                acc[1][nt] = __builtin_amdgcn_mfma_f32_16x16x32_bf16(a1, bb, acc[1][nt], 0, 0, 0);
            }
        }
    }

    // ---- epilogue ---------------------------------------------------------
    const int prow = (lane >> 4) * 4;
#pragma unroll
    for (int mt = 0; mt < 2; ++mt) {
#pragma unroll
        for (int nt = 0; nt < 4; ++nt) {
            const int oc = wv * 64 + nt * 16 + l15;
            float* op = out + ((size_t)b * OC + oc) * HW + px0 + mt * 16 + prow;
            *(float4*)op = *(float4*)&acc[mt][nt];
        }
    }
}

// ---------------------------------------------------------------------------
// Launcher. Inputs: kernel, search, Toffset_w, Toffset_b, Tdeform_w,
//                   Soffset_w, Soffset_b, Sdeform_w
// Outputs: kernel_out[16,256,16,16], search_out[16,256,32,32],
//          kernel_offset[16,18,16,16], search_offset[16,18,32,32]
// d_ws usage: 13.2 MB (weights bf16 2.66 MB + HWC inputs 10.5 MB).
// ---------------------------------------------------------------------------
extern "C" void kernel_launch(void* const* d_in, const int* in_sizes, int n_in,
                              void* d_out, int out_size, void* d_ws, size_t ws_size,
                              hipStream_t stream) {
    const float* kin = (const float*)d_in[0];
    const float* sin_ = (const float*)d_in[1];
    const float* tow = (const float*)d_in[2];
    const float* tob = (const float*)d_in[3];
    const float* tdw = (const float*)d_in[4];
    const float* sow = (const float*)d_in[5];
    const float* sob = (const float*)d_in[6];
    const float* sdw = (const float*)d_in[7];

    float* out = (float*)d_out;
    float* out_k  = out;                                      // 16*256*16*16
    float* out_s  = out_k + (size_t)16 * 256 * 16 * 16;       // 16*256*32*32
    float* out_ko = out_s + (size_t)16 * 256 * 32 * 32;       // 16*18*16*16
    float* out_so = out_ko + (size_t)16 * 18 * 16 * 16;       // 16*18*32*32

    ushort_t* wk_d = (ushort_t*)d_ws;                 // [256][2304] tap-major
    ushort_t* ws_d = wk_d + N_DW;
    ushort_t* wk_o = ws_d + N_DW;                     // [32][2304] tap-major
    ushort_t* ws_o = wk_o + N_OW;
    ushort_t* xt_k = ws_o + N_OW;                     // [16][256][256] HWC bf16
    ushort_t* xt_s = xt_k + (size_t)16 * 256 * 256;   // [16][1024][256]

    const int n_cvt = 2 * N_DW + 2 * N_OW;
    cvt_w_k<<<dim3((n_cvt + 255) / 256), 256, 0, stream>>>(
        tdw, sdw, tow, sow, wk_d, ws_d, wk_o, ws_o);

    transpose_k<<<dim3(320), 256, 0, stream>>>(kin, sin_, xt_k, xt_s);

    conv_gemm_k<<<dim3(320), 256, 0, stream>>>(
        xt_k, wk_o, tob, out_ko, xt_s, ws_o, sob, out_so);

    deform_gemm_k<<<dim3(768), 256, 0, stream>>>(
        xt_k, out_ko, wk_d, out_k, xt_s, out_so, ws_d, out_s);
}

// Round 5
// 258.718 us; speedup vs baseline: 4.3931x; 1.0125x over previous
//
#include <hip/hip_runtime.h>

#define CIN   256
#define OC    256
#define K_TOT 2304             // 256*9
#define CCH   32               // channels per K-chunk
#define NCHK  8                // K chunks
#define KCH   288              // k-values per chunk (tap-major: k = tap*32 + c)
#define SSTR  296              // LDS row stride (bf16 elems), 16B-aligned, padded

#define N_DW  (OC * K_TOT)     // deform weight elements (589824)
#define N_OW  (32 * K_TOT)     // padded offset weight elements (73728)
#define N_CVT (2 * N_DW + 2 * N_OW)          // 1327104 (divisible by 1024)
#define CVT_BLOCKS (N_CVT / 4 / 256)         // 1296

typedef short  bf16x8 __attribute__((ext_vector_type(8)));
typedef float  f32x4  __attribute__((ext_vector_type(4)));
typedef unsigned short ushort_t;

__device__ __forceinline__ ushort_t f2bf(float f) {
    unsigned u = __builtin_bit_cast(unsigned, f);
    u += 0x7fffu + ((u >> 16) & 1u);          // RNE
    return (ushort_t)(u >> 16);
}
__device__ __forceinline__ float bf2f(short s) {
    return __builtin_bit_cast(float, ((unsigned)(unsigned short)s) << 16);
}

// ---------------------------------------------------------------------------
// prep kernel: (a) weight fp32->bf16 cvt with tap-major K permutation
//   dst[oc][cc][tap][cl] = src[oc][cc*32+cl][tap]   (4 elems/thread)
// (b) input transpose NCHW fp32 -> HWC bf16.
// blockIdx.x < CVT_BLOCKS -> cvt; else transpose (320 blocks).
// ---------------------------------------------------------------------------
__global__ __launch_bounds__(256) void prep_k(
    const float* __restrict__ tdw, const float* __restrict__ sdw,
    const float* __restrict__ tow, const float* __restrict__ sow,
    const float* __restrict__ kin, const float* __restrict__ sin_,
    ushort_t* __restrict__ wk_d, ushort_t* __restrict__ ws_d,
    ushort_t* __restrict__ wk_o, ushort_t* __restrict__ ws_o,
    ushort_t* __restrict__ xt_k, ushort_t* __restrict__ xt_s)
{
    __shared__ ushort_t tile[64][264];    // transpose staging

    if (blockIdx.x < CVT_BLOCKS) {
        const int i = (blockIdx.x * 256 + threadIdx.x) * 4;
        const float* src; ushort_t* dst; int j; bool offw = false;
        if (i < N_DW)                    { src = tdw; dst = wk_d; j = i; }
        else if (i < 2 * N_DW)           { src = sdw; dst = ws_d; j = i - N_DW; }
        else if (i < 2 * N_DW + N_OW)    { src = tow; dst = wk_o; j = i - 2 * N_DW; offw = true; }
        else                             { src = sow; dst = ws_o; j = i - 2 * N_DW - N_OW; offw = true; }
        const int oc = j / K_TOT;
        const int k  = j - oc * K_TOT;
        const int cc = k / KCH;
        const int r  = k - cc * KCH;     // r%4==0, so cl..cl+3 share one tap
        const int tap = r >> 5;
        const int cl  = r & 31;
        ushort4 o4 = {0, 0, 0, 0};
        if (!offw || oc < 18) {
            const float* sp = &src[((size_t)oc * CIN + cc * 32 + cl) * 9 + tap];
            o4.x = f2bf(sp[0]); o4.y = f2bf(sp[9]); o4.z = f2bf(sp[18]); o4.w = f2bf(sp[27]);
        }
        *(ushort4*)&dst[j] = o4;
        return;
    }

    // ---- transpose branch -------------------------------------------------
    const int bx2 = blockIdx.x - CVT_BLOCKS;     // 0..319
    int H, W, b, px0; const float* x; ushort_t* xt;
    if (bx2 < 64) {                       // kernel: 16 b * 4 tiles
        H = 16; W = 16; x = kin; xt = xt_k;
        b = bx2 >> 2; px0 = (bx2 & 3) * 64;
    } else {                              // search: 16 b * 16 tiles
        int t2 = bx2 - 64;
        H = 32; W = 32; x = sin_; xt = xt_s;
        b = t2 >> 4; px0 = (t2 & 15) * 64;
    }
    const int HW = H * W;
    const int t = threadIdx.x, lane = t & 63, wv = t >> 6;
    const float* xb = x + (size_t)b * CIN * HW;

    for (int it = 0; it < 16; ++it) {
        const int ch = wv * 64 + it * 4 + (lane >> 4);
        const int pq = (lane & 15) * 4;
        float4 v = *(const float4*)&xb[(size_t)ch * HW + px0 + pq];
        tile[pq + 0][ch] = f2bf(v.x);
        tile[pq + 1][ch] = f2bf(v.y);
        tile[pq + 2][ch] = f2bf(v.z);
        tile[pq + 3][ch] = f2bf(v.w);
    }
    __syncthreads();
    for (int it = 0; it < 8; ++it) {
        const int px = it * 8 + wv * 2 + (lane >> 5);
        const int cg = (lane & 31) * 8;
        bf16x8 v = *(const bf16x8*)&tile[px][cg];
        *(bf16x8*)&xt[((size_t)b * HW + px0 + px) * 256 + cg] = v;
    }
}

// ---------------------------------------------------------------------------
// Offset conv as bf16 MFMA GEMM from HWC input. M=64 px/block (4 waves x 16),
// N=32 (18 real oc), K=2304 tap-major. A-frags straight from global HWC.
// blockIdx.x < 64 -> kernel branch, else search. (grid 320)
// ---------------------------------------------------------------------------
__global__ __launch_bounds__(256) void conv_gemm_k(
    const ushort_t* __restrict__ xt_k, const ushort_t* __restrict__ kwgt,
    const float* __restrict__ kbias, float* __restrict__ kout,
    const ushort_t* __restrict__ xt_s, const ushort_t* __restrict__ swgt,
    const float* __restrict__ sbias, float* __restrict__ sout)
{
    int H, W, b, px0;
    const ushort_t* xt; const ushort_t* wgt; const float* bias; float* out;
    if (blockIdx.x < 64) {
        H = 16; W = 16; xt = xt_k; wgt = kwgt; bias = kbias; out = kout;
        b = blockIdx.x >> 2; px0 = (blockIdx.x & 3) * 64;
    } else {
        int t2 = blockIdx.x - 64;
        H = 32; W = 32; xt = xt_s; wgt = swgt; bias = sbias; out = sout;
        b = t2 >> 4; px0 = (t2 & 15) * 64;
    }
    const int HW = H * W;
    const int t = threadIdx.x, lane = t & 63, wv = t >> 6;
    const int l15 = lane & 15;
    const int cg8 = (lane >> 4) * 8;

    const int px = px0 + wv * 16 + l15;
    const int h  = px / W;
    const int wc = px - h * W;
    const ushort_t* xtb = xt + (size_t)b * HW * 256;

    f32x4 acc[2] = {};

    for (int cc = 0; cc < NCHK; ++cc) {
#pragma unroll
        for (int ks = 0; ks < 9; ++ks) {          // ks == tap
            const int y  = h + ks / 3 - 1;
            const int xx = wc + ks % 3 - 1;
            const bool ok = ((unsigned)y < (unsigned)H) && ((unsigned)xx < (unsigned)W);
            bf16x8 a = {};
            if (ok) a = *(const bf16x8*)&xtb[(size_t)(y * W + xx) * 256 + cc * 32 + cg8];
            const size_t kg = (size_t)cc * KCH + ks * 32 + cg8;
#pragma unroll
            for (int nt = 0; nt < 2; ++nt) {
                bf16x8 bb = *(const bf16x8*)&wgt[(size_t)(nt * 16 + l15) * K_TOT + kg];
                acc[nt] = __builtin_amdgcn_mfma_f32_16x16x32_bf16(a, bb, acc[nt], 0, 0, 0);
            }
        }
    }

    const int prow = (lane >> 4) * 4;
#pragma unroll
    for (int nt = 0; nt < 2; ++nt) {
        const int oc = nt * 16 + l15;
        if (oc < 18) {
            const float bs = bias[oc];
            float4 r = { acc[nt].x + bs, acc[nt].y + bs, acc[nt].z + bs, acc[nt].w + bs };
            *(float4*)(out + ((size_t)b * 18 + oc) * HW + px0 + wv * 16 + prow) = r;
        }
    }
}

// ---------------------------------------------------------------------------
// Deformable conv, bf16 MFMA GEMM from HWC. M=32, N=256, K=2304 tap-major.
// Block = 512 threads = 8 waves; wave w: oc column [w*32, w*32+32) (nt=2),
// both m-tiles. B loaded once per block. Double-buffered smp -> ONE barrier
// per K-chunk: a wave finishing MFMA(cc) immediately issues gather loads for
// cc+1 (into buffer cc+1&1) while other waves are still in MFMA(cc).
// grid: 128 kernel-branch blocks + 512 search = 640.
// ---------------------------------------------------------------------------
__device__ __forceinline__ void dcn_load4(
    bf16x8* c, const ushort_t* __restrict__ xtb, int4 id, int cb)
{
    c[0] = *(const bf16x8*)&xtb[(size_t)id.x * 256 + cb];
    c[1] = *(const bf16x8*)&xtb[(size_t)id.y * 256 + cb];
    c[2] = *(const bf16x8*)&xtb[(size_t)id.z * 256 + cb];
    c[3] = *(const bf16x8*)&xtb[(size_t)id.w * 256 + cb];
}
__device__ __forceinline__ void dcn_proc(
    ushort_t (*sw)[SSTR], int px, int tap, int cg, const bf16x8* c, float4 wt)
{
    bf16x8 r;
#pragma unroll
    for (int j = 0; j < 8; ++j) {
        const float v = wt.x * bf2f(c[0][j]) + wt.y * bf2f(c[1][j])
                      + wt.z * bf2f(c[2][j]) + wt.w * bf2f(c[3][j]);
        r[j] = (short)f2bf(v);
    }
    *(bf16x8*)&sw[px][tap * 32 + cg * 8] = r;
}

__global__ __launch_bounds__(512, 4) void deform_gemm_k(
    const ushort_t* __restrict__ xt_k, const float* __restrict__ koffs,
    const ushort_t* __restrict__ kwgt, float* __restrict__ kout,
    const ushort_t* __restrict__ xt_s, const float* __restrict__ soffs,
    const ushort_t* __restrict__ swgt_, float* __restrict__ sout)
{
    __shared__ __align__(16) ushort_t smp[2][32][SSTR];  // 37.9 KB (dbuf)
    __shared__ __align__(16) int      sidx[32][9][4];    // 4.6 KB
    __shared__ __align__(16) float    swt [32][9][4];    // 4.6 KB

    int H, W, b, px0;
    const ushort_t* xt; const float* offs; const ushort_t* wgt; float* out;
    if (blockIdx.x < 128) {               // kernel: 16 b * 8 tiles = 128
        H = 16; W = 16; xt = xt_k; offs = koffs; wgt = kwgt; out = kout;
        b = blockIdx.x >> 3; px0 = (blockIdx.x & 7) * 32;
    } else {                              // search: 16 b * 32 tiles = 512
        int t2 = blockIdx.x - 128;
        H = 32; W = 32; xt = xt_s; offs = soffs; wgt = swgt_; out = sout;
        b = t2 >> 5; px0 = (t2 & 31) * 32;
    }
    const int HW = H * W;
    const int t = threadIdx.x, lane = t & 63, wv = t >> 6;

    // ---- phase 0: bilinear params, one (px,tap) unit per thread -----------
    if (t < 288) {
        const int p = t / 9, k = t - 9 * p;
        const int pix = px0 + p;
        const int h  = pix / W;
        const int wc = pix - h * W;
        const float* ob = offs + (size_t)b * 18 * HW;
        const float dy = ob[(2 * k    ) * HW + pix];
        const float dx = ob[(2 * k + 1) * HW + pix];
        const float sy = (float)(h  + k / 3 - 1) + dy;
        const float sx = (float)(wc + k % 3 - 1) + dx;
        const float y0f = floorf(sy), x0f = floorf(sx);
        const float ly = sy - y0f, lx = sx - x0f;
        const int y0 = (int)y0f, x0 = (int)x0f;
#pragma unroll
        for (int j = 0; j < 4; ++j) {
            const int yy = y0 + (j >> 1);
            const int xx = x0 + (j & 1);
            const bool ok = ((unsigned)yy < (unsigned)H) && ((unsigned)xx < (unsigned)W);
            sidx[p][k][j] = min(max(yy, 0), H - 1) * W + min(max(xx, 0), W - 1);
            const float wj = ((j >> 1) ? ly : 1.f - ly) * ((j & 1) ? lx : 1.f - lx);
            swt[p][k][j] = ok ? wj : 0.f;
        }
    }
    __syncthreads();

    const ushort_t* xtb = xt + (size_t)b * HW * 256;
    const int l15 = lane & 15;
    const int cg8 = (lane >> 4) * 8;
    const int ocb = wv * 32;              // this wave's oc column

    // gather units: s = tap*128 + px*4 + cg; 1152 units, 3 per thread
    int upx[3], utap[3], ucg[3];
    int4 uid[3]; float4 uwt[3];
#pragma unroll
    for (int u = 0; u < 3; ++u) {
        const int s = t + u * 512;
        if (s < 1152) {
            utap[u] = s >> 7;
            const int r = s & 127;
            upx[u] = r >> 2; ucg[u] = r & 3;
            uid[u] = *(const int4*)  sidx[upx[u]][utap[u]];
            uwt[u] = *(const float4*)swt [upx[u]][utap[u]];
        }
    }
    const bool live2 = (t < 128);         // unit u=2 exists only for t<128

    f32x4 acc[2][2] = {};                 // [mt][nt]

    for (int cc = 0; cc < NCHK; ++cc) {
        ushort_t (*sw)[SSTR] = smp[cc & 1];
        const int cb = cc * 32;
        // ---- gather (3-deep pipelined) ------------------------------------
        {
            bf16x8 c0[4], c1[4], c2[4];
            dcn_load4(c0, xtb, uid[0], cb + ucg[0] * 8);
            dcn_load4(c1, xtb, uid[1], cb + ucg[1] * 8);
            if (live2) dcn_load4(c2, xtb, uid[2], cb + ucg[2] * 8);
            dcn_proc(sw, upx[0], utap[0], ucg[0], c0, uwt[0]);
            dcn_proc(sw, upx[1], utap[1], ucg[1], c1, uwt[1]);
            if (live2) dcn_proc(sw, upx[2], utap[2], ucg[2], c2, uwt[2]);
        }
        __syncthreads();                  // single barrier per chunk (dbuf)
        // ---- MFMA: 9 K-steps of 32 ----------------------------------------
#pragma unroll
        for (int ks = 0; ks < 9; ++ks) {
            bf16x8 a0 = *(const bf16x8*)&sw[l15     ][ks * 32 + cg8];
            bf16x8 a1 = *(const bf16x8*)&sw[16 + l15][ks * 32 + cg8];
            const size_t kg = (size_t)cc * KCH + ks * 32 + cg8;
            bf16x8 b0 = *(const bf16x8*)&wgt[(size_t)(ocb      + l15) * K_TOT + kg];
            bf16x8 b1 = *(const bf16x8*)&wgt[(size_t)(ocb + 16 + l15) * K_TOT + kg];
            acc[0][0] = __builtin_amdgcn_mfma_f32_16x16x32_bf16(a0, b0, acc[0][0], 0, 0, 0);
            acc[1][0] = __builtin_amdgcn_mfma_f32_16x16x32_bf16(a1, b0, acc[1][0], 0, 0, 0);
            acc[0][1] = __builtin_amdgcn_mfma_f32_16x16x32_bf16(a0, b1, acc[0][1], 0, 0, 0);
            acc[1][1] = __builtin_amdgcn_mfma_f32_16x16x32_bf16(a1, b1, acc[1][1], 0, 0, 0);
        }
    }

    // ---- epilogue ---------------------------------------------------------
    const int prow = (lane >> 4) * 4;
#pragma unroll
    for (int mt = 0; mt < 2; ++mt) {
#pragma unroll
        for (int nt = 0; nt < 2; ++nt) {
            const int oc = ocb + nt * 16 + l15;
            float* op = out + ((size_t)b * OC + oc) * HW + px0 + mt * 16 + prow;
            *(float4*)op = *(float4*)&acc[mt][nt];
        }
    }
}

// ---------------------------------------------------------------------------
// Launcher. Inputs: kernel, search, Toffset_w, Toffset_b, Tdeform_w,
//                   Soffset_w, Soffset_b, Sdeform_w
// Outputs: kernel_out[16,256,16,16], search_out[16,256,32,32],
//          kernel_offset[16,18,16,16], search_offset[16,18,32,32]
// d_ws: 13.2 MB (bf16 weights 2.66 MB + HWC inputs 10.5 MB).
// ---------------------------------------------------------------------------
extern "C" void kernel_launch(void* const* d_in, const int* in_sizes, int n_in,
                              void* d_out, int out_size, void* d_ws, size_t ws_size,
                              hipStream_t stream) {
    const float* kin = (const float*)d_in[0];
    const float* sin_ = (const float*)d_in[1];
    const float* tow = (const float*)d_in[2];
    const float* tob = (const float*)d_in[3];
    const float* tdw = (const float*)d_in[4];
    const float* sow = (const float*)d_in[5];
    const float* sob = (const float*)d_in[6];
    const float* sdw = (const float*)d_in[7];

    float* out = (float*)d_out;
    float* out_k  = out;                                      // 16*256*16*16
    float* out_s  = out_k + (size_t)16 * 256 * 16 * 16;       // 16*256*32*32
    float* out_ko = out_s + (size_t)16 * 256 * 32 * 32;       // 16*18*16*16
    float* out_so = out_ko + (size_t)16 * 18 * 16 * 16;       // 16*18*32*32

    ushort_t* wk_d = (ushort_t*)d_ws;                 // [256][2304] tap-major
    ushort_t* ws_d = wk_d + N_DW;
    ushort_t* wk_o = ws_d + N_DW;                     // [32][2304] tap-major
    ushort_t* ws_o = wk_o + N_OW;
    ushort_t* xt_k = ws_o + N_OW;                     // [16][256][256] HWC bf16
    ushort_t* xt_s = xt_k + (size_t)16 * 256 * 256;   // [16][1024][256]

    prep_k<<<dim3(CVT_BLOCKS + 320), 256, 0, stream>>>(
        tdw, sdw, tow, sow, kin, sin_,
        wk_d, ws_d, wk_o, ws_o, xt_k, xt_s);

    conv_gemm_k<<<dim3(320), 256, 0, stream>>>(
        xt_k, wk_o, tob, out_ko, xt_s, ws_o, sob, out_so);

    deform_gemm_k<<<dim3(640), 512, 0, stream>>>(
        xt_k, out_ko, wk_d, out_k, xt_s, out_so, ws_d, out_s);
}

// Round 6
// 244.667 us; speedup vs baseline: 4.6454x; 1.0574x over previous
//
#include <hip/hip_runtime.h>

#define CIN   256
#define OC    256
#define K_TOT 2304             // 256*9
#define CCH   32               // channels per K-chunk
#define NCHK  8                // K chunks
#define KCH   288              // k-values per chunk (tap-major: k = tap*32 + c)
#define SSTR  296              // LDS row stride (bf16 elems), 16B-aligned, padded

#define N_DW  (OC * K_TOT)     // deform weight elements (589824)
#define N_OW  (32 * K_TOT)     // padded offset weight elements (73728)
#define N_CVT (2 * N_DW + 2 * N_OW)          // 1327104
#define CVT_BLOCKS (N_CVT / 4 / 256)         // 1296

typedef short  bf16x8 __attribute__((ext_vector_type(8)));
typedef float  f32x4  __attribute__((ext_vector_type(4)));
typedef unsigned short ushort_t;

__device__ __forceinline__ ushort_t f2bf(float f) {
    unsigned u = __builtin_bit_cast(unsigned, f);
    u += 0x7fffu + ((u >> 16) & 1u);          // RNE
    return (ushort_t)(u >> 16);
}
__device__ __forceinline__ float bf2f(short s) {
    return __builtin_bit_cast(float, ((unsigned)(unsigned short)s) << 16);
}

// ---------------------------------------------------------------------------
// prep kernel: (a) weight fp32->bf16 cvt with tap-major K permutation
//   dst[oc][cc][tap][cl] = src[oc][cc*32+cl][tap]   (4 elems/thread)
// (b) input transpose NCHW fp32 -> HWC bf16.
// blockIdx.x < CVT_BLOCKS -> cvt; else transpose (320 blocks).
// ---------------------------------------------------------------------------
__global__ __launch_bounds__(256) void prep_k(
    const float* __restrict__ tdw, const float* __restrict__ sdw,
    const float* __restrict__ tow, const float* __restrict__ sow,
    const float* __restrict__ kin, const float* __restrict__ sin_,
    ushort_t* __restrict__ wk_d, ushort_t* __restrict__ ws_d,
    ushort_t* __restrict__ wk_o, ushort_t* __restrict__ ws_o,
    ushort_t* __restrict__ xt_k, ushort_t* __restrict__ xt_s)
{
    __shared__ ushort_t tile[64][264];    // transpose staging

    if (blockIdx.x < CVT_BLOCKS) {
        const int i = (blockIdx.x * 256 + threadIdx.x) * 4;
        const float* src; ushort_t* dst; int j; bool offw = false;
        if (i < N_DW)                    { src = tdw; dst = wk_d; j = i; }
        else if (i < 2 * N_DW)           { src = sdw; dst = ws_d; j = i - N_DW; }
        else if (i < 2 * N_DW + N_OW)    { src = tow; dst = wk_o; j = i - 2 * N_DW; offw = true; }
        else                             { src = sow; dst = ws_o; j = i - 2 * N_DW - N_OW; offw = true; }
        const int oc = j / K_TOT;
        const int k  = j - oc * K_TOT;
        const int cc = k / KCH;
        const int r  = k - cc * KCH;     // r%4==0, so cl..cl+3 share one tap
        const int tap = r >> 5;
        const int cl  = r & 31;
        ushort4 o4 = {0, 0, 0, 0};
        if (!offw || oc < 18) {
            const float* sp = &src[((size_t)oc * CIN + cc * 32 + cl) * 9 + tap];
            o4.x = f2bf(sp[0]); o4.y = f2bf(sp[9]); o4.z = f2bf(sp[18]); o4.w = f2bf(sp[27]);
        }
        *(ushort4*)&dst[j] = o4;
        return;
    }

    // ---- transpose branch -------------------------------------------------
    const int bx2 = blockIdx.x - CVT_BLOCKS;     // 0..319
    int H, W, b, px0; const float* x; ushort_t* xt;
    if (bx2 < 64) {                       // kernel: 16 b * 4 tiles
        H = 16; W = 16; x = kin; xt = xt_k;
        b = bx2 >> 2; px0 = (bx2 & 3) * 64;
    } else {                              // search: 16 b * 16 tiles
        int t2 = bx2 - 64;
        H = 32; W = 32; x = sin_; xt = xt_s;
        b = t2 >> 4; px0 = (t2 & 15) * 64;
    }
    const int HW = H * W;
    const int t = threadIdx.x, lane = t & 63, wv = t >> 6;
    const float* xb = x + (size_t)b * CIN * HW;

    for (int it = 0; it < 16; ++it) {
        const int ch = wv * 64 + it * 4 + (lane >> 4);
        const int pq = (lane & 15) * 4;
        float4 v = *(const float4*)&xb[(size_t)ch * HW + px0 + pq];
        tile[pq + 0][ch] = f2bf(v.x);
        tile[pq + 1][ch] = f2bf(v.y);
        tile[pq + 2][ch] = f2bf(v.z);
        tile[pq + 3][ch] = f2bf(v.w);
    }
    __syncthreads();
    for (int it = 0; it < 8; ++it) {
        const int px = it * 8 + wv * 2 + (lane >> 5);
        const int cg = (lane & 31) * 8;
        bf16x8 v = *(const bf16x8*)&tile[px][cg];
        *(bf16x8*)&xt[((size_t)b * HW + px0 + px) * 256 + cg] = v;
    }
}

// ---------------------------------------------------------------------------
// Offset conv as bf16 MFMA GEMM from HWC. M=16 px/block, N=32, K=2304.
// 1280 blocks (5/CU). Block = 4 waves: wave = (nt = wv&1, K-half = wv>>1),
// each wave does 4 K-chunks x 9 taps = 36 indep load+MFMA steps; K-halves
// combined through a 2 KB LDS reduce. launch_bounds(256,2) -> 128 VGPRs for
// deep load flight.
// blockIdx.x < 256 -> kernel branch, else search (1024).
// ---------------------------------------------------------------------------
__global__ __launch_bounds__(256, 2) void conv_gemm_k(
    const ushort_t* __restrict__ xt_k, const ushort_t* __restrict__ kwgt,
    const float* __restrict__ kbias, float* __restrict__ kout,
    const ushort_t* __restrict__ xt_s, const ushort_t* __restrict__ swgt,
    const float* __restrict__ sbias, float* __restrict__ sout)
{
    __shared__ float sred[2][64][4];      // [nt][lane][reg]

    int H, W, b, px0;
    const ushort_t* xt; const ushort_t* wgt; const float* bias; float* out;
    if (blockIdx.x < 256) {               // kernel: 16 b * 16 tiles
        H = 16; W = 16; xt = xt_k; wgt = kwgt; bias = kbias; out = kout;
        b = blockIdx.x >> 4; px0 = (blockIdx.x & 15) * 16;
    } else {                              // search: 16 b * 64 tiles
        int t2 = blockIdx.x - 256;
        H = 32; W = 32; xt = xt_s; wgt = swgt; bias = sbias; out = sout;
        b = t2 >> 6; px0 = (t2 & 63) * 16;
    }
    const int HW = H * W;
    const int t = threadIdx.x, lane = t & 63, wv = t >> 6;
    const int l15 = lane & 15;
    const int cg8 = (lane >> 4) * 8;
    const int nt = wv & 1;                // n-tile
    const int kh = wv >> 1;               // K-half

    const int px = px0 + l15;
    const int h  = px / W;
    const int wc = px - h * W;
    const ushort_t* xtb = xt + (size_t)b * HW * 256;

    // per-tap address + validity (lane-varying)
    int  aoff[9];
    bool aok [9];
#pragma unroll
    for (int ks = 0; ks < 9; ++ks) {
        const int y  = h + ks / 3 - 1;
        const int xx = wc + ks % 3 - 1;
        aok [ks] = ((unsigned)y < (unsigned)H) && ((unsigned)xx < (unsigned)W);
        aoff[ks] = aok[ks] ? ((y * W + xx) * 256 + cg8) : 0;
    }
    const ushort_t* wrow = wgt + (size_t)(nt * 16 + l15) * K_TOT + cg8;

    f32x4 acc = {};
    for (int cc = kh * 4; cc < kh * 4 + 4; ++cc) {
#pragma unroll
        for (int ks = 0; ks < 9; ++ks) {
            bf16x8 a = {};
            if (aok[ks]) a = *(const bf16x8*)&xtb[aoff[ks] + cc * 32];
            bf16x8 bb = *(const bf16x8*)&wrow[(size_t)cc * KCH + ks * 32];
            acc = __builtin_amdgcn_mfma_f32_16x16x32_bf16(a, bb, acc, 0, 0, 0);
        }
    }

    if (kh == 1) *(float4*)&sred[nt][lane][0] = *(float4*)&acc;
    __syncthreads();
    if (kh == 0) {
        const float4 o = *(const float4*)&sred[nt][lane][0];
        const int oc = nt * 16 + l15;
        if (oc < 18) {
            const float bs = bias[oc];
            const int prow = (lane >> 4) * 4;
            float4 r = { acc.x + o.x + bs, acc.y + o.y + bs,
                         acc.z + o.z + bs, acc.w + o.w + bs };
            *(float4*)(out + ((size_t)b * 18 + oc) * HW + px0 + prow) = r;
        }
    }
}

// ---------------------------------------------------------------------------
// Deformable conv, bf16 MFMA GEMM from HWC. M=32, N=256, K=2304 tap-major.
// Block = 512 thr = 8 waves; wave = oc column [wv*32,+32), both m-tiles.
// Double-buffered smp, ONE barrier/chunk. B-fragments rolled through a 2-ks
// register double-buffer (bX/bY) so the MFMA phase never waits on global B.
// grid: 128 kernel-branch + 512 search = 640.
// ---------------------------------------------------------------------------
__device__ __forceinline__ void dcn_load4(
    bf16x8* c, const ushort_t* __restrict__ xtb, int4 id, int cb)
{
    c[0] = *(const bf16x8*)&xtb[(size_t)id.x * 256 + cb];
    c[1] = *(const bf16x8*)&xtb[(size_t)id.y * 256 + cb];
    c[2] = *(const bf16x8*)&xtb[(size_t)id.z * 256 + cb];
    c[3] = *(const bf16x8*)&xtb[(size_t)id.w * 256 + cb];
}
__device__ __forceinline__ void dcn_proc(
    ushort_t (*sw)[SSTR], int px, int tap, int cg, const bf16x8* c, float4 wt)
{
    bf16x8 r;
#pragma unroll
    for (int j = 0; j < 8; ++j) {
        const float v = wt.x * bf2f(c[0][j]) + wt.y * bf2f(c[1][j])
                      + wt.z * bf2f(c[2][j]) + wt.w * bf2f(c[3][j]);
        r[j] = (short)f2bf(v);
    }
    *(bf16x8*)&sw[px][tap * 32 + cg * 8] = r;
}
__device__ __forceinline__ void ldb2(
    bf16x8 (*B)[2], const ushort_t* __restrict__ w0,
    const ushort_t* __restrict__ w1, size_t kg0, int ks0)
{
    B[0][0] = *(const bf16x8*)&w0[kg0 + (size_t)ks0 * 32];
    B[0][1] = *(const bf16x8*)&w1[kg0 + (size_t)ks0 * 32];
    B[1][0] = *(const bf16x8*)&w0[kg0 + (size_t)(ks0 + 1) * 32];
    B[1][1] = *(const bf16x8*)&w1[kg0 + (size_t)(ks0 + 1) * 32];
}
__device__ __forceinline__ void mm2(
    f32x4 (*acc)[2], bf16x8 (*B)[2], ushort_t (*sw)[SSTR],
    int l15, int cg8, int ks0, int n)
{
#pragma unroll
    for (int i = 0; i < n; ++i) {
        bf16x8 a0 = *(const bf16x8*)&sw[l15     ][(ks0 + i) * 32 + cg8];
        bf16x8 a1 = *(const bf16x8*)&sw[16 + l15][(ks0 + i) * 32 + cg8];
        acc[0][0] = __builtin_amdgcn_mfma_f32_16x16x32_bf16(a0, B[i][0], acc[0][0], 0, 0, 0);
        acc[1][0] = __builtin_amdgcn_mfma_f32_16x16x32_bf16(a1, B[i][0], acc[1][0], 0, 0, 0);
        acc[0][1] = __builtin_amdgcn_mfma_f32_16x16x32_bf16(a0, B[i][1], acc[0][1], 0, 0, 0);
        acc[1][1] = __builtin_amdgcn_mfma_f32_16x16x32_bf16(a1, B[i][1], acc[1][1], 0, 0, 0);
    }
}

__global__ __launch_bounds__(512, 4) void deform_gemm_k(
    const ushort_t* __restrict__ xt_k, const float* __restrict__ koffs,
    const ushort_t* __restrict__ kwgt, float* __restrict__ kout,
    const ushort_t* __restrict__ xt_s, const float* __restrict__ soffs,
    const ushort_t* __restrict__ swgt_, float* __restrict__ sout)
{
    __shared__ __align__(16) ushort_t smp[2][32][SSTR];  // 37.9 KB (dbuf)
    __shared__ __align__(16) int      sidx[32][9][4];    // 4.6 KB
    __shared__ __align__(16) float    swt [32][9][4];    // 4.6 KB

    int H, W, b, px0;
    const ushort_t* xt; const float* offs; const ushort_t* wgt; float* out;
    if (blockIdx.x < 128) {               // kernel: 16 b * 8 tiles
        H = 16; W = 16; xt = xt_k; offs = koffs; wgt = kwgt; out = kout;
        b = blockIdx.x >> 3; px0 = (blockIdx.x & 7) * 32;
    } else {                              // search: 16 b * 32 tiles
        int t2 = blockIdx.x - 128;
        H = 32; W = 32; xt = xt_s; offs = soffs; wgt = swgt_; out = sout;
        b = t2 >> 5; px0 = (t2 & 31) * 32;
    }
    const int HW = H * W;
    const int t = threadIdx.x, lane = t & 63, wv = t >> 6;

    // ---- phase 0: bilinear params, one (px,tap) unit per thread -----------
    if (t < 288) {
        const int p = t / 9, k = t - 9 * p;
        const int pix = px0 + p;
        const int h  = pix / W;
        const int wc = pix - h * W;
        const float* ob = offs + (size_t)b * 18 * HW;
        const float dy = ob[(2 * k    ) * HW + pix];
        const float dx = ob[(2 * k + 1) * HW + pix];
        const float sy = (float)(h  + k / 3 - 1) + dy;
        const float sx = (float)(wc + k % 3 - 1) + dx;
        const float y0f = floorf(sy), x0f = floorf(sx);
        const float ly = sy - y0f, lx = sx - x0f;
        const int y0 = (int)y0f, x0 = (int)x0f;
#pragma unroll
        for (int j = 0; j < 4; ++j) {
            const int yy = y0 + (j >> 1);
            const int xx = x0 + (j & 1);
            const bool ok = ((unsigned)yy < (unsigned)H) && ((unsigned)xx < (unsigned)W);
            sidx[p][k][j] = min(max(yy, 0), H - 1) * W + min(max(xx, 0), W - 1);
            const float wj = ((j >> 1) ? ly : 1.f - ly) * ((j & 1) ? lx : 1.f - lx);
            swt[p][k][j] = ok ? wj : 0.f;
        }
    }
    __syncthreads();

    const ushort_t* xtb = xt + (size_t)b * HW * 256;
    const int l15 = lane & 15;
    const int cg8 = (lane >> 4) * 8;
    const int ocb = wv * 32;

    // gather unit geometry only (id/wt re-read from LDS each chunk to save
    // 24 persistent VGPRs for load flight)
    int upx[3], utap[3], ucg[3];
#pragma unroll
    for (int u = 0; u < 3; ++u) {
        const int s = t + u * 512;
        if (s < 1152) {
            utap[u] = s >> 7;
            const int r = s & 127;
            upx[u] = r >> 2; ucg[u] = r & 3;
        }
    }
    const bool live2 = (t < 128);

    const ushort_t* wrow0 = wgt + (size_t)(ocb      + l15) * K_TOT + cg8;
    const ushort_t* wrow1 = wgt + (size_t)(ocb + 16 + l15) * K_TOT + cg8;

    f32x4 acc[2][2] = {};

    for (int cc = 0; cc < NCHK; ++cc) {
        ushort_t (*sw)[SSTR] = smp[cc & 1];
        const int cb = cc * 32;
        const size_t kg0 = (size_t)cc * KCH;

        // ---- gather -------------------------------------------------------
        bf16x8 c0[4], c1[4], c2[4];
        const int4   id0 = *(const int4*)  sidx[upx[0]][utap[0]];
        const float4 wt0 = *(const float4*)swt [upx[0]][utap[0]];
        const int4   id1 = *(const int4*)  sidx[upx[1]][utap[1]];
        const float4 wt1 = *(const float4*)swt [upx[1]][utap[1]];
        dcn_load4(c0, xtb, id0, cb + ucg[0] * 8);
        dcn_load4(c1, xtb, id1, cb + ucg[1] * 8);
        int4 id2 = {}; float4 wt2 = {};
        if (live2) {
            id2 = *(const int4*)  sidx[upx[2]][utap[2]];
            wt2 = *(const float4*)swt [upx[2]][utap[2]];
            dcn_load4(c2, xtb, id2, cb + ucg[2] * 8);
        }
        dcn_proc(sw, upx[0], utap[0], ucg[0], c0, wt0);
        // B group 0 (ks 0,1) -- independent of LDS, issued pre-barrier
        bf16x8 bX[2][2], bY[2][2];
        ldb2(bX, wrow0, wrow1, kg0, 0);
        dcn_proc(sw, upx[1], utap[1], ucg[1], c1, wt1);
        if (live2) dcn_proc(sw, upx[2], utap[2], ucg[2], c2, wt2);
        __syncthreads();

        // ---- MFMA phase: rolled 2-ks register double-buffer ---------------
        ldb2(bY, wrow0, wrow1, kg0, 2);  mm2(acc, bX, sw, l15, cg8, 0, 2);
        ldb2(bX, wrow0, wrow1, kg0, 4);  mm2(acc, bY, sw, l15, cg8, 2, 2);
        ldb2(bY, wrow0, wrow1, kg0, 6);  mm2(acc, bX, sw, l15, cg8, 4, 2);
        bX[0][0] = *(const bf16x8*)&wrow0[kg0 + 8 * 32];
        bX[0][1] = *(const bf16x8*)&wrow1[kg0 + 8 * 32];
        mm2(acc, bY, sw, l15, cg8, 6, 2);
        mm2(acc, bX, sw, l15, cg8, 8, 1);
    }

    // ---- epilogue ---------------------------------------------------------
    const int prow = (lane >> 4) * 4;
#pragma unroll
    for (int mt = 0; mt < 2; ++mt) {
#pragma unroll
        for (int nt = 0; nt < 2; ++nt) {
            const int oc = ocb + nt * 16 + l15;
            float* op = out + ((size_t)b * OC + oc) * HW + px0 + mt * 16 + prow;
            *(float4*)op = *(float4*)&acc[mt][nt];
        }
    }
}

// ---------------------------------------------------------------------------
// Launcher. Inputs: kernel, search, Toffset_w, Toffset_b, Tdeform_w,
//                   Soffset_w, Soffset_b, Sdeform_w
// Outputs: kernel_out[16,256,16,16], search_out[16,256,32,32],
//          kernel_offset[16,18,16,16], search_offset[16,18,32,32]
// d_ws: 13.2 MB (bf16 weights 2.66 MB + HWC inputs 10.5 MB).
// ---------------------------------------------------------------------------
extern "C" void kernel_launch(void* const* d_in, const int* in_sizes, int n_in,
                              void* d_out, int out_size, void* d_ws, size_t ws_size,
                              hipStream_t stream) {
    const float* kin = (const float*)d_in[0];
    const float* sin_ = (const float*)d_in[1];
    const float* tow = (const float*)d_in[2];
    const float* tob = (const float*)d_in[3];
    const float* tdw = (const float*)d_in[4];
    const float* sow = (const float*)d_in[5];
    const float* sob = (const float*)d_in[6];
    const float* sdw = (const float*)d_in[7];

    float* out = (float*)d_out;
    float* out_k  = out;                                      // 16*256*16*16
    float* out_s  = out_k + (size_t)16 * 256 * 16 * 16;       // 16*256*32*32
    float* out_ko = out_s + (size_t)16 * 256 * 32 * 32;       // 16*18*16*16
    float* out_so = out_ko + (size_t)16 * 18 * 16 * 16;       // 16*18*32*32

    ushort_t* wk_d = (ushort_t*)d_ws;                 // [256][2304] tap-major
    ushort_t* ws_d = wk_d + N_DW;
    ushort_t* wk_o = ws_d + N_DW;                     // [32][2304] tap-major
    ushort_t* ws_o = wk_o + N_OW;
    ushort_t* xt_k = ws_o + N_OW;                     // [16][256][256] HWC bf16
    ushort_t* xt_s = xt_k + (size_t)16 * 256 * 256;   // [16][1024][256]

    prep_k<<<dim3(CVT_BLOCKS + 320), 256, 0, stream>>>(
        tdw, sdw, tow, sow, kin, sin_,
        wk_d, ws_d, wk_o, ws_o, xt_k, xt_s);

    conv_gemm_k<<<dim3(1280), 256, 0, stream>>>(
        xt_k, wk_o, tob, out_ko, xt_s, ws_o, sob, out_so);

    deform_gemm_k<<<dim3(640), 512, 0, stream>>>(
        xt_k, out_ko, wk_d, out_k, xt_s, out_so, ws_d, out_s);
}